// Round 1
// baseline (577.832 us; speedup 1.0000x reference)
//
#include <hip/hip_runtime.h>
#include <hip/hip_bf16.h>
#include <math.h>

typedef unsigned short u16;
typedef __attribute__((ext_vector_type(8))) __bf16 bf16x8;
typedef __attribute__((ext_vector_type(4))) float f32x4;
typedef __attribute__((ext_vector_type(8))) u16 u16x8;
typedef __attribute__((ext_vector_type(4))) u16 u16x4;

#define DEV static __device__ __forceinline__

DEV u16 f2bf(float x) {
  __bf16 b = (__bf16)x;
  return __builtin_bit_cast(u16, b);
}
DEV float bf2f(u16 u) {
  unsigned v = ((unsigned)u) << 16;
  return __builtin_bit_cast(float, v);
}

DEV void gl_lds16(const u16* g, u16* l) {
  __builtin_amdgcn_global_load_lds(
      (const __attribute__((address_space(1))) void*)g,
      (__attribute__((address_space(3))) void*)l, 16, 0, 0);
}

DEV float waveRedSum(float v) {
  v += __shfl_xor(v, 1);  v += __shfl_xor(v, 2);  v += __shfl_xor(v, 4);
  v += __shfl_xor(v, 8);  v += __shfl_xor(v, 16); v += __shfl_xor(v, 32);
  return v;
}

// ---------------------------------------------------------------- cvt f32->bf16
__global__ __launch_bounds__(256)
void cvt_f32_bf16(const float* __restrict__ in, u16* __restrict__ out, int n8) {
  int i = blockIdx.x * 256 + threadIdx.x;
  if (i >= n8) return;
  const float4 a = *(const float4*)(in + (size_t)i * 8);
  const float4 b = *(const float4*)(in + (size_t)i * 8 + 4);
  u16x8 o;
  o[0] = f2bf(a.x); o[1] = f2bf(a.y); o[2] = f2bf(a.z); o[3] = f2bf(a.w);
  o[4] = f2bf(b.x); o[5] = f2bf(b.y); o[6] = f2bf(b.z); o[7] = f2bf(b.w);
  *(u16x8*)(out + (size_t)i * 8) = o;
}

// ------------------------------------------------ pack Wq/Wk/Wv [H,D,DH] -> bf16 [3072][1024] (N,K)
__global__ __launch_bounds__(256)
void pack_wqkv(const float* __restrict__ Wq, const float* __restrict__ Wk,
               const float* __restrict__ Wv, u16* __restrict__ out) {
  __shared__ float tl[64][65];
  int bid = blockIdx.x;              // 3 * 16 * 16 = 768
  int which = bid / 256;
  int rem = bid % 256;
  int h = rem / 16, dt = rem % 16;
  const float* W = (which == 0) ? Wq : (which == 1) ? Wk : Wv;
  int t = threadIdx.x, tx = t & 63, ty = t >> 6;
  const float* src = W + (size_t)h * 65536 + (size_t)dt * 64 * 64;  // [d][e]
#pragma unroll
  for (int i = 0; i < 16; ++i) {
    int dr = ty * 16 + i;
    tl[dr][tx] = src[(size_t)dr * 64 + tx];
  }
  __syncthreads();
#pragma unroll
  for (int i = 0; i < 16; ++i) {
    int e = ty * 16 + i;
    out[(size_t)(which * 1024 + h * 64 + e) * 1024 + dt * 64 + tx] = f2bf(tl[tx][e]);
  }
}

// ------------------------------------------------ pack W [K][N] -> Wt bf16 [N][K]
__global__ __launch_bounds__(256)
void pack_wt(const float* __restrict__ W, u16* __restrict__ out, int K, int N) {
  __shared__ float tl[64][65];
  int ntiles = N >> 6;
  int kt = blockIdx.x / ntiles, nt = blockIdx.x % ntiles;
  int t = threadIdx.x, tx = t & 63, ty = t >> 6;
#pragma unroll
  for (int i = 0; i < 16; ++i) {
    int kr = ty * 16 + i;
    tl[kr][tx] = W[(size_t)(kt * 64 + kr) * N + nt * 64 + tx];
  }
  __syncthreads();
#pragma unroll
  for (int i = 0; i < 16; ++i) {
    int nr = ty * 16 + i;
    out[(size_t)(nt * 64 + nr) * K + kt * 64 + tx] = f2bf(tl[tx][nr]);
  }
}

// ------------------------------------------------ transpose V part of qkv -> vt [B*H*DH][S]
__global__ __launch_bounds__(256)
void transpose_v(const u16* __restrict__ qkv, u16* __restrict__ vt) {
  __shared__ u16 tl[64][65];
  int bid = blockIdx.x;        // bh*16 + st
  int bh = bid >> 4, st = bid & 15;
  int b = bh >> 4, h = bh & 15;
  int t = threadIdx.x, tx = t & 63, ty = t >> 6;
  const u16* src = qkv + (size_t)(b * 1024 + st * 64) * 3072 + 2048 + h * 64;
#pragma unroll
  for (int i = 0; i < 16; ++i) {
    int sr = ty * 16 + i;
    tl[sr][tx] = src[(size_t)sr * 3072 + tx];
  }
  __syncthreads();
  u16* dst = vt + (size_t)(bh * 64) * 1024 + st * 64;
#pragma unroll
  for (int i = 0; i < 16; ++i) {
    int e = ty * 16 + i;
    dst[(size_t)e * 1024 + tx] = tl[tx][e];
  }
}

// ------------------------------------------------ GEMM: C[M,N] = A[M,K] * Bt[N,K]^T
// EPI: 0 = bf16 out; 1 = f32 out + bias; 2 = bf16 out + bias + exact GELU
template <int EPI>
__global__ __launch_bounds__(256, 2)
void gemm_bt(const u16* __restrict__ A, const u16* __restrict__ Bt,
             void* __restrict__ Cout, const float* __restrict__ bias,
             int M, int N, int K) {
  __shared__ __align__(16) u16 As[128 * 32];
  __shared__ __align__(16) u16 Bs[128 * 32];
  const int t = threadIdx.x;
  const int lane = t & 63, w = t >> 6;
  const int li = lane & 15, lg = lane >> 4;
  const int tiles_n = N >> 7;
  const int m0 = (blockIdx.x / tiles_n) << 7;
  const int n0 = (blockIdx.x % tiles_n) << 7;
  const int wm = (w >> 1) << 6, wn = (w & 1) << 6;

  f32x4 acc[4][4] = {};

  const int rowA = t >> 2, kcA = (t & 3) * 8;
  u16* aBase0 = &As[(size_t)(w * 64) * 8];
  u16* aBase1 = &As[(size_t)(256 + w * 64) * 8];
  u16* bBase0 = &Bs[(size_t)(w * 64) * 8];
  u16* bBase1 = &Bs[(size_t)(256 + w * 64) * 8];

  for (int k0 = 0; k0 < K; k0 += 32) {
    gl_lds16(A  + (size_t)(m0 + rowA) * K      + k0 + kcA, aBase0);
    gl_lds16(A  + (size_t)(m0 + 64 + rowA) * K + k0 + kcA, aBase1);
    gl_lds16(Bt + (size_t)(n0 + rowA) * K      + k0 + kcA, bBase0);
    gl_lds16(Bt + (size_t)(n0 + 64 + rowA) * K + k0 + kcA, bBase1);
    __syncthreads();
    bf16x8 af[4], bfr[4];
#pragma unroll
    for (int i = 0; i < 4; ++i)
      af[i] = *(const bf16x8*)&As[(wm + i * 16 + li) * 32 + lg * 8];
#pragma unroll
    for (int i = 0; i < 4; ++i)
      bfr[i] = *(const bf16x8*)&Bs[(wn + i * 16 + li) * 32 + lg * 8];
#pragma unroll
    for (int i = 0; i < 4; ++i)
#pragma unroll
      for (int j = 0; j < 4; ++j)
        acc[i][j] = __builtin_amdgcn_mfma_f32_16x16x32_bf16(af[i], bfr[j], acc[i][j], 0, 0, 0);
    __syncthreads();
  }

  const int colBase = n0 + wn + li;
#pragma unroll
  for (int i = 0; i < 4; ++i) {
#pragma unroll
    for (int j = 0; j < 4; ++j) {
      int col = colBase + j * 16;
      float bv = (EPI >= 1) ? bias[col] : 0.0f;
#pragma unroll
      for (int r = 0; r < 4; ++r) {
        int row = m0 + wm + i * 16 + lg * 4 + r;
        float v = acc[i][j][r];
        if (EPI >= 1) v += bv;
        if (EPI == 2) v = 0.5f * v * (1.0f + erff(v * 0.70710678118654752f));
        if (EPI == 1) ((float*)Cout)[(size_t)row * N + col] = v;
        else          ((u16*)Cout)[(size_t)row * N + col] = f2bf(v);
      }
    }
  }
}

// ------------------------------------------------ flash attention
// qkv: [B*S][3072] bf16 (q | k | v cols, col = h*64+e); vt: [B*H*64][S] bf16
// ctx: [B*S][1024] bf16
__global__ __launch_bounds__(256, 2)
void attn_kernel(const u16* __restrict__ qkv, const u16* __restrict__ vt,
                 u16* __restrict__ ctx) {
  __shared__ __align__(16) u16 Plds[4 * 16 * 72];
  const int t = threadIdx.x, lane = t & 63, w = t >> 6;
  const int li = lane & 15, lg = lane >> 4;
  const int bid = blockIdx.x;     // bh*16 + qt
  const int bh = bid >> 4, qt = bid & 15;
  const int b = bh >> 4, h = bh & 15;

  const int qrow0 = b * 1024 + qt * 64 + w * 16;
  const u16* qbase = qkv + (size_t)qrow0 * 3072 + h * 64;
  const u16* kbase = qkv + (size_t)(b * 1024) * 3072 + 1024 + h * 64;
  const u16* vbase = vt + (size_t)(bh * 64) * 1024;

  bf16x8 qf0 = *(const bf16x8*)&qbase[(size_t)li * 3072 + lg * 8];
  bf16x8 qf1 = *(const bf16x8*)&qbase[(size_t)li * 3072 + 32 + lg * 8];

  float m_run[4], l_run[4];
  f32x4 o[4] = {};
#pragma unroll
  for (int r = 0; r < 4; ++r) { m_run[r] = -1e30f; l_run[r] = 0.0f; }

  u16* pw = &Plds[w * 16 * 72];

  for (int tt = 0; tt < 16; ++tt) {
    f32x4 s[4] = {};
#pragma unroll
    for (int fn = 0; fn < 4; ++fn) {
      const u16* kr = kbase + (size_t)(tt * 64 + fn * 16 + li) * 3072;
      bf16x8 k0 = *(const bf16x8*)&kr[lg * 8];
      bf16x8 k1 = *(const bf16x8*)&kr[32 + lg * 8];
      s[fn] = __builtin_amdgcn_mfma_f32_16x16x32_bf16(qf0, k0, s[fn], 0, 0, 0);
      s[fn] = __builtin_amdgcn_mfma_f32_16x16x32_bf16(qf1, k1, s[fn], 0, 0, 0);
    }
#pragma unroll
    for (int fn = 0; fn < 4; ++fn) s[fn] *= 0.125f;

    float nm[4], alpha[4];
#pragma unroll
    for (int r = 0; r < 4; ++r) {
      float tm = fmaxf(fmaxf(s[0][r], s[1][r]), fmaxf(s[2][r], s[3][r]));
      tm = fmaxf(tm, __shfl_xor(tm, 1));
      tm = fmaxf(tm, __shfl_xor(tm, 2));
      tm = fmaxf(tm, __shfl_xor(tm, 4));
      tm = fmaxf(tm, __shfl_xor(tm, 8));
      nm[r] = fmaxf(m_run[r], tm);
      alpha[r] = __expf(m_run[r] - nm[r]);
      m_run[r] = nm[r];
    }
    float p[4][4];
#pragma unroll
    for (int fn = 0; fn < 4; ++fn)
#pragma unroll
      for (int r = 0; r < 4; ++r)
        p[fn][r] = __expf(s[fn][r] - nm[r]);
#pragma unroll
    for (int r = 0; r < 4; ++r) {
      float rs = p[0][r] + p[1][r] + p[2][r] + p[3][r];
      rs += __shfl_xor(rs, 1);
      rs += __shfl_xor(rs, 2);
      rs += __shfl_xor(rs, 4);
      rs += __shfl_xor(rs, 8);
      l_run[r] = l_run[r] * alpha[r] + rs;
    }
#pragma unroll
    for (int fd = 0; fd < 4; ++fd)
#pragma unroll
      for (int r = 0; r < 4; ++r)
        o[fd][r] *= alpha[r];

    // P -> LDS (bf16), then reload as PV A-fragments
#pragma unroll
    for (int fn = 0; fn < 4; ++fn)
#pragma unroll
      for (int r = 0; r < 4; ++r)
        pw[(lg * 4 + r) * 72 + fn * 16 + li] = f2bf(p[fn][r]);
    asm volatile("s_waitcnt lgkmcnt(0)" ::: "memory");
    bf16x8 pa0 = *(const bf16x8*)&pw[li * 72 + lg * 8];
    bf16x8 pa1 = *(const bf16x8*)&pw[li * 72 + 32 + lg * 8];

#pragma unroll
    for (int fd = 0; fd < 4; ++fd) {
      const u16* vr = vbase + (size_t)(fd * 16 + li) * 1024 + tt * 64;
      bf16x8 v0 = *(const bf16x8*)&vr[lg * 8];
      bf16x8 v1 = *(const bf16x8*)&vr[32 + lg * 8];
      o[fd] = __builtin_amdgcn_mfma_f32_16x16x32_bf16(pa0, v0, o[fd], 0, 0, 0);
      o[fd] = __builtin_amdgcn_mfma_f32_16x16x32_bf16(pa1, v1, o[fd], 0, 0, 0);
    }
  }

#pragma unroll
  for (int r = 0; r < 4; ++r) {
    float inv = 1.0f / l_run[r];
    int row = qrow0 + lg * 4 + r;
#pragma unroll
    for (int fd = 0; fd < 4; ++fd)
      ctx[(size_t)row * 1024 + h * 64 + fd * 16 + li] = f2bf(o[fd][r] * inv);
  }
}

// ------------------------------------------------ LayerNorm (residual fused)
// MODE 0: in1 f32, in2 f32 -> out bf16     (h = LN(x+attn))
// MODE 1: in1 bf16, in2 f32 -> out f32     (out = LN(h+ff2))
template <int MODE>
__global__ __launch_bounds__(256)
void ln_kernel(const void* __restrict__ in1v, const float* __restrict__ in2,
               const float* __restrict__ g, const float* __restrict__ bt,
               void* __restrict__ outv) {
  __shared__ float red[4];
  const int row = blockIdx.x;
  const int t = threadIdx.x;
  const int c = t * 4;
  const size_t base = (size_t)row * 1024 + c;

  float a0, a1, a2, a3;
  {
    const float4 y = *(const float4*)(in2 + base);
    if (MODE == 0) {
      const float4 x = *(const float4*)((const float*)in1v + base);
      a0 = x.x + y.x; a1 = x.y + y.y; a2 = x.z + y.z; a3 = x.w + y.w;
    } else {
      u16x4 xb = *(const u16x4*)((const u16*)in1v + base);
      a0 = bf2f(xb[0]) + y.x; a1 = bf2f(xb[1]) + y.y;
      a2 = bf2f(xb[2]) + y.z; a3 = bf2f(xb[3]) + y.w;
    }
  }
  float sum = waveRedSum(a0 + a1 + a2 + a3);
  if ((t & 63) == 0) red[t >> 6] = sum;
  __syncthreads();
  float mean = (red[0] + red[1] + red[2] + red[3]) * (1.0f / 1024.0f);
  __syncthreads();
  float d0 = a0 - mean, d1 = a1 - mean, d2 = a2 - mean, d3 = a3 - mean;
  float sq = waveRedSum(d0 * d0 + d1 * d1 + d2 * d2 + d3 * d3);
  if ((t & 63) == 0) red[t >> 6] = sq;
  __syncthreads();
  float var = (red[0] + red[1] + red[2] + red[3]) * (1.0f / 1023.0f);
  float inv = rsqrtf(var + 1e-5f);
  const float4 gv = *(const float4*)(g + c);
  const float4 bv = *(const float4*)(bt + c);
  float o0 = d0 * inv * gv.x + bv.x;
  float o1 = d1 * inv * gv.y + bv.y;
  float o2 = d2 * inv * gv.z + bv.z;
  float o3 = d3 * inv * gv.w + bv.w;
  if (MODE == 0) {
    u16x4 ob; ob[0] = f2bf(o0); ob[1] = f2bf(o1); ob[2] = f2bf(o2); ob[3] = f2bf(o3);
    *(u16x4*)((u16*)outv + base) = ob;
  } else {
    float4 of; of.x = o0; of.y = o1; of.z = o2; of.w = o3;
    *(float4*)((float*)outv + base) = of;
  }
}

// ================================================================ launcher
extern "C" void kernel_launch(void* const* d_in, const int* in_sizes, int n_in,
                              void* d_out, int out_size, void* d_ws, size_t ws_size,
                              hipStream_t stream) {
  const float* x  = (const float*)d_in[0];
  const float* Wq = (const float*)d_in[1];
  const float* Wk = (const float*)d_in[2];
  const float* Wv = (const float*)d_in[3];
  const float* Wo = (const float*)d_in[4];
  const float* bo = (const float*)d_in[5];
  const float* g1 = (const float*)d_in[6];
  const float* b1 = (const float*)d_in[7];
  const float* W1 = (const float*)d_in[8];
  const float* c1 = (const float*)d_in[9];
  const float* W2 = (const float*)d_in[10];
  const float* c2 = (const float*)d_in[11];
  const float* g2 = (const float*)d_in[12];
  const float* b2 = (const float*)d_in[13];
  float* out = (float*)d_out;

  // workspace layout (bytes); total use = 159,383,552
  char* ws = (char*)d_ws;
  u16* xb     = (u16*)(ws + 0);           // 16,777,216  (reused as h_b later)
  u16* wqkv_b = (u16*)(ws + 16777216);    //  6,291,456
  u16* wo_b   = (u16*)(ws + 23068672);    //  2,097,152
  u16* w1_b   = (u16*)(ws + 25165824);    //  8,388,608
  u16* w2_b   = (u16*)(ws + 33554432);    //  8,388,608
  char* R1 = ws + 41943040;               // 117,440,512 region, aliased over time
  u16*  qkv  = (u16*)(R1);                 // 50,331,648   live: steps 6-8
  u16*  vt   = (u16*)(R1 + 50331648);      // 16,777,216   live: 7-8
  u16*  ctx  = (u16*)(R1 + 67108864);      // 16,777,216   live: 8-9
  float* attn = (float*)(R1 + 83886080);   // 33,554,432   live: 9-10
  u16*  ff1  = (u16*)(R1);                 // 67,108,864   live: 11-12 (aliases qkv+vt)
  float* ff2 = (float*)(R1 + 67108864);    // 33,554,432   live: 12-13 (aliases ctx+attn head)
  u16*  h_b  = xb;                         // live: 10-13 (aliases xb)

  cvt_f32_bf16<<<4096, 256, 0, stream>>>(x, xb, 1048576);
  pack_wqkv<<<768, 256, 0, stream>>>(Wq, Wk, Wv, wqkv_b);
  pack_wt<<<256, 256, 0, stream>>>(Wo, wo_b, 1024, 1024);
  pack_wt<<<1024, 256, 0, stream>>>(W1, w1_b, 1024, 4096);
  pack_wt<<<1024, 256, 0, stream>>>(W2, w2_b, 4096, 1024);

  gemm_bt<0><<<64 * 24, 256, 0, stream>>>(xb, wqkv_b, qkv, nullptr, 8192, 3072, 1024);
  transpose_v<<<2048, 256, 0, stream>>>(qkv, vt);
  attn_kernel<<<2048, 256, 0, stream>>>(qkv, vt, ctx);
  gemm_bt<1><<<64 * 8, 256, 0, stream>>>(ctx, wo_b, attn, bo, 8192, 1024, 1024);
  ln_kernel<0><<<8192, 256, 0, stream>>>(x, attn, g1, b1, h_b);
  gemm_bt<2><<<64 * 32, 256, 0, stream>>>(h_b, w1_b, ff1, c1, 8192, 4096, 1024);
  gemm_bt<1><<<64 * 8, 256, 0, stream>>>(ff1, w2_b, ff2, c2, 8192, 1024, 4096);
  ln_kernel<1><<<8192, 256, 0, stream>>>(h_b, ff2, g2, b2, out);
}

// Round 4
// 491.374 us; speedup vs baseline: 1.1760x; 1.1760x over previous
//
#include <hip/hip_runtime.h>
#include <hip/hip_bf16.h>
#include <math.h>

typedef unsigned short u16;
typedef unsigned int u32;
typedef __attribute__((ext_vector_type(8))) __bf16 bf16x8;
typedef __attribute__((ext_vector_type(4))) float f32x4;
typedef __attribute__((ext_vector_type(16))) float f32x16;
typedef __attribute__((ext_vector_type(8))) u16 u16x8;
typedef __attribute__((ext_vector_type(4))) u16 u16x4;
typedef __attribute__((ext_vector_type(4))) u32 u32x4;

#define DEV static __device__ __forceinline__

DEV u16 f2bf(float x) {
  __bf16 b = (__bf16)x;
  return __builtin_bit_cast(u16, b);
}
DEV float bf2f(u16 u) {
  unsigned v = ((unsigned)u) << 16;
  return __builtin_bit_cast(float, v);
}

DEV void gl_lds16(const u16* g, u16* l) {
  __builtin_amdgcn_global_load_lds(
      (const __attribute__((address_space(1))) void*)g,
      (__attribute__((address_space(3))) void*)l, 16, 0, 0);
}

DEV float waveRedSum(float v) {
  v += __shfl_xor(v, 1);  v += __shfl_xor(v, 2);  v += __shfl_xor(v, 4);
  v += __shfl_xor(v, 8);  v += __shfl_xor(v, 16); v += __shfl_xor(v, 32);
  return v;
}

// --- attention helpers -------------------------------------------------------
DEV float exp2_fast(float x) {
  float r;
  asm("v_exp_f32 %0, %1" : "=v"(r) : "v"(x));
  return r;
}
DEV float vmax16(f32x16 v) {
  float a = fmaxf(v[0], v[1]), b = fmaxf(v[2], v[3]);
  float c = fmaxf(v[4], v[5]), d = fmaxf(v[6], v[7]);
  float e = fmaxf(v[8], v[9]), f = fmaxf(v[10], v[11]);
  float g = fmaxf(v[12], v[13]), h = fmaxf(v[14], v[15]);
  a = fmaxf(a, b); c = fmaxf(c, d); e = fmaxf(e, f); g = fmaxf(g, h);
  return fmaxf(fmaxf(a, c), fmaxf(e, g));
}
DEV float vsum16(f32x16 v) {
  float a = v[0] + v[1], b = v[2] + v[3], c = v[4] + v[5], d = v[6] + v[7];
  float e = v[8] + v[9], f = v[10] + v[11], g = v[12] + v[13], h = v[14] + v[15];
  a += b; c += d; e += f; g += h;
  return (a + c) + (e + g);
}
DEV f32x16 mfma32(bf16x8 a, bf16x8 b, f32x16 c) {
  return __builtin_amdgcn_mfma_f32_32x32x16_bf16(a, b, c, 0, 0, 0);
}
// pack two f32 -> one u32 of two bf16 (elem0 = lo 16 bits), RNE via (__bf16) cast
DEV u32 pack2(float lo, float hi2) {
  return ((u32)f2bf(hi2) << 16) | (u32)f2bf(lo);
}
// P^T (verified MFMA C layout: row=(r&3)+8*(r>>2)+4*hi, col=q=l31) ->
// two PV B-fragments in "as-if contiguous" placement (elem e of half hi = row 8*hi+e
// within each 16-row group). Direction-safe: partner-half data via __shfl_xor(32).
DEV void pack_pb(const f32x16& s, int hi, bf16x8* out) {
  u32 c0 = pack2(s[0], s[1]),   c1 = pack2(s[2], s[3]);
  u32 c2 = pack2(s[4], s[5]),   c3 = pack2(s[6], s[7]);
  u32 c4 = pack2(s[8], s[9]),   c5 = pack2(s[10], s[11]);
  u32 c6 = pack2(s[12], s[13]), c7 = pack2(s[14], s[15]);
  u32 d0 = (u32)__shfl_xor((int)c0, 32), d1 = (u32)__shfl_xor((int)c1, 32);
  u32 d2 = (u32)__shfl_xor((int)c2, 32), d3 = (u32)__shfl_xor((int)c3, 32);
  u32 d4 = (u32)__shfl_xor((int)c4, 32), d5 = (u32)__shfl_xor((int)c5, 32);
  u32 d6 = (u32)__shfl_xor((int)c6, 32), d7 = (u32)__shfl_xor((int)c7, 32);
  // rows map (derivation in journal): hi=0 lane needs rows {0..7} = own c0,c1 + partner c0,c1
  //                                   hi=1 lane needs rows {8..15} = partner c2,c3 + own c2,c3
  u32x4 f0, f1;
  f0[0] = hi ? d2 : c0;  f0[1] = hi ? d3 : c1;
  f0[2] = hi ? c2 : d0;  f0[3] = hi ? c3 : d1;
  f1[0] = hi ? d6 : c4;  f1[1] = hi ? d7 : c5;
  f1[2] = hi ? c6 : d4;  f1[3] = hi ? c7 : d5;
  out[0] = __builtin_bit_cast(bf16x8, f0);
  out[1] = __builtin_bit_cast(bf16x8, f1);
}

// ---------------------------------------------------------------- cvt f32->bf16
__global__ __launch_bounds__(256)
void cvt_f32_bf16(const float* __restrict__ in, u16* __restrict__ out, int n8) {
  int i = blockIdx.x * 256 + threadIdx.x;
  if (i >= n8) return;
  const float4 a = *(const float4*)(in + (size_t)i * 8);
  const float4 b = *(const float4*)(in + (size_t)i * 8 + 4);
  u16x8 o;
  o[0] = f2bf(a.x); o[1] = f2bf(a.y); o[2] = f2bf(a.z); o[3] = f2bf(a.w);
  o[4] = f2bf(b.x); o[5] = f2bf(b.y); o[6] = f2bf(b.z); o[7] = f2bf(b.w);
  *(u16x8*)(out + (size_t)i * 8) = o;
}

// ------------------------------------------------ pack Wq/Wk/Wv [H,D,DH] -> bf16 [3072][1024] (N,K)
__global__ __launch_bounds__(256)
void pack_wqkv(const float* __restrict__ Wq, const float* __restrict__ Wk,
               const float* __restrict__ Wv, u16* __restrict__ out) {
  __shared__ float tl[64][65];
  int bid = blockIdx.x;              // 3 * 16 * 16 = 768
  int which = bid / 256;
  int rem = bid % 256;
  int h = rem / 16, dt = rem % 16;
  const float* W = (which == 0) ? Wq : (which == 1) ? Wk : Wv;
  int t = threadIdx.x, tx = t & 63, ty = t >> 6;
  const float* src = W + (size_t)h * 65536 + (size_t)dt * 64 * 64;  // [d][e]
#pragma unroll
  for (int i = 0; i < 16; ++i) {
    int dr = ty * 16 + i;
    tl[dr][tx] = src[(size_t)dr * 64 + tx];
  }
  __syncthreads();
#pragma unroll
  for (int i = 0; i < 16; ++i) {
    int e = ty * 16 + i;
    out[(size_t)(which * 1024 + h * 64 + e) * 1024 + dt * 64 + tx] = f2bf(tl[tx][e]);
  }
}

// ------------------------------------------------ pack W [K][N] -> Wt bf16 [N][K]
__global__ __launch_bounds__(256)
void pack_wt(const float* __restrict__ W, u16* __restrict__ out, int K, int N) {
  __shared__ float tl[64][65];
  int ntiles = N >> 6;
  int kt = blockIdx.x / ntiles, nt = blockIdx.x % ntiles;
  int t = threadIdx.x, tx = t & 63, ty = t >> 6;
#pragma unroll
  for (int i = 0; i < 16; ++i) {
    int kr = ty * 16 + i;
    tl[kr][tx] = W[(size_t)(kt * 64 + kr) * N + nt * 64 + tx];
  }
  __syncthreads();
#pragma unroll
  for (int i = 0; i < 16; ++i) {
    int nr = ty * 16 + i;
    out[(size_t)(nt * 64 + nr) * K + kt * 64 + tx] = f2bf(tl[tx][nr]);
  }
}

// ------------------------------------------------ GEMM: C[M,N] = A[M,K] * Bt[N,K]^T
// EPI: 0 = bf16 out; 1 = f32 out + bias; 2 = bf16 out + bias + exact GELU
// EPI: 3 = QKV pack: q->qp, k->kp, v->vt (transposed)
template <int EPI>
__global__ __launch_bounds__(256, 2)
void gemm_bt(const u16* __restrict__ A, const u16* __restrict__ Bt,
             void* __restrict__ Cout, const float* __restrict__ bias,
             int M, int N, int K,
             u16* __restrict__ qp_out, u16* __restrict__ kp_out,
             u16* __restrict__ vt_out) {
  __shared__ __align__(16) u16 As[128 * 32];
  __shared__ __align__(16) u16 Bs[128 * 32];
  const int t = threadIdx.x;
  const int lane = t & 63, w = t >> 6;
  const int li = lane & 15, lg = lane >> 4;
  const int tiles_n = N >> 7;
  const int m0 = (blockIdx.x / tiles_n) << 7;
  const int n0 = (blockIdx.x % tiles_n) << 7;
  const int wm = (w >> 1) << 6, wn = (w & 1) << 6;

  f32x4 acc[4][4] = {};

  const int rowA = t >> 2, kcA = (t & 3) * 8;
  u16* aBase0 = &As[(size_t)(w * 64) * 8];
  u16* aBase1 = &As[(size_t)(256 + w * 64) * 8];
  u16* bBase0 = &Bs[(size_t)(w * 64) * 8];
  u16* bBase1 = &Bs[(size_t)(256 + w * 64) * 8];

  for (int k0 = 0; k0 < K; k0 += 32) {
    gl_lds16(A  + (size_t)(m0 + rowA) * K      + k0 + kcA, aBase0);
    gl_lds16(A  + (size_t)(m0 + 64 + rowA) * K + k0 + kcA, aBase1);
    gl_lds16(Bt + (size_t)(n0 + rowA) * K      + k0 + kcA, bBase0);
    gl_lds16(Bt + (size_t)(n0 + 64 + rowA) * K + k0 + kcA, bBase1);
    __syncthreads();
    bf16x8 af[4], bfr[4];
#pragma unroll
    for (int i = 0; i < 4; ++i)
      af[i] = *(const bf16x8*)&As[(wm + i * 16 + li) * 32 + lg * 8];
#pragma unroll
    for (int i = 0; i < 4; ++i)
      bfr[i] = *(const bf16x8*)&Bs[(wn + i * 16 + li) * 32 + lg * 8];
#pragma unroll
    for (int i = 0; i < 4; ++i)
#pragma unroll
      for (int j = 0; j < 4; ++j)
        acc[i][j] = __builtin_amdgcn_mfma_f32_16x16x32_bf16(af[i], bfr[j], acc[i][j], 0, 0, 0);
    __syncthreads();
  }

  if constexpr (EPI == 3) {
    const int which = n0 >> 10;                 // block-uniform: 0=q 1=k 2=v
    const int colb = (n0 & 1023) + wn + li;     // col within the 1024 group
#pragma unroll
    for (int i = 0; i < 4; ++i) {
      const int row0 = m0 + wm + i * 16 + lg * 4;
      const int bb = row0 >> 10;
      const int s0r = row0 & 1023;
#pragma unroll
      for (int j = 0; j < 4; ++j) {
        const int c = colb + j * 16;
        const int hh = c >> 6, e = c & 63;
        const size_t hb = ((size_t)(bb * 16 + hh)) << 16;   // bh * 1024*64
        if (which == 2) {
          u16x4 pk;
#pragma unroll
          for (int r = 0; r < 4; ++r) pk[r] = f2bf(acc[i][j][r]);
          *(u16x4*)(vt_out + hb + ((size_t)e << 10) + s0r) = pk;
        } else {
          u16* dst = (which == 0) ? qp_out : kp_out;
#pragma unroll
          for (int r = 0; r < 4; ++r)
            dst[hb + (size_t)(s0r + r) * 64 + e] = f2bf(acc[i][j][r]);
        }
      }
    }
    return;
  }

  const int colBase = n0 + wn + li;
#pragma unroll
  for (int i = 0; i < 4; ++i) {
#pragma unroll
    for (int j = 0; j < 4; ++j) {
      int col = colBase + j * 16;
      float bv = (EPI >= 1) ? bias[col] : 0.0f;
#pragma unroll
      for (int r = 0; r < 4; ++r) {
        int row = m0 + wm + i * 16 + lg * 4 + r;
        float v = acc[i][j][r];
        if (EPI >= 1) v += bv;
        if (EPI == 2) v = 0.5f * v * (1.0f + erff(v * 0.70710678118654752f));
        if (EPI == 1) ((float*)Cout)[(size_t)row * N + col] = v;
        else          ((u16*)Cout)[(size_t)row * N + col] = f2bf(v);
      }
    }
  }
}

// ------------------------------------------------ flash attention, 32x32 swapped-QK^T
// qp/kp: [BH][S][64] bf16 (unscaled); vt: [BH][64][S] bf16
// ctx: [B*S][1024] bf16.  No LDS, no barriers; softmax fully in-register.
// All cross-lane ops via __shfl_xor (no permlane/cvt_pk semantics assumptions).
__global__ __launch_bounds__(256, 2)
void attn32(const u16* __restrict__ qp, const u16* __restrict__ kp,
            const u16* __restrict__ vt, u16* __restrict__ ctx) {
  const int t = threadIdx.x, l = t & 63, w = t >> 6;
  const int l31 = l & 31, hi = l >> 5;
  const int bid = blockIdx.x;        // bh*8 + qt
  const int bh = bid >> 3, qt = bid & 7;
  const int b = bh >> 4, h = bh & 15;
  const int qg = qt * 128 + w * 32;  // this wave's q-tile start
  const size_t base = (size_t)bh << 16;
  const float SC = 0.18033688011112042f;  // 0.125 * log2(e)

  // Q as B-fragments: n = q = l31, k(d) = f*16 + 8*hi + e (as-if-contiguous; cancels vs K)
  const u16* qrow = qp + base + (size_t)(qg + l31) * 64 + 8 * hi;
  bf16x8 qb[4];
#pragma unroll
  for (int f = 0; f < 4; ++f) qb[f] = *(const bf16x8*)(qrow + f * 16);

  f32x16 o0 = {}, o1 = {};           // O^T tiles: d 0-31, 32-63 for q = l31
  float m_run = -1e30f, l_run = 0.0f;

  const u16* kb_base = kp + base + (size_t)l31 * 64 + 8 * hi;
  const u16* vb_base = vt + base + (size_t)l31 * 1024 + 8 * hi;

  for (int kb = 0; kb < 16; ++kb) {
    // K as A-fragments: m = k_local = l31, k(d) = f*16 + 8*hi + e
    const u16* kptr = kb_base + (size_t)kb * 64 * 64;
    bf16x8 ka0[4], ka1[4];
#pragma unroll
    for (int f = 0; f < 4; ++f) {
      ka0[f] = *(const bf16x8*)(kptr + f * 16);
      ka1[f] = *(const bf16x8*)(kptr + 2048 + f * 16);  // +32 rows
    }
    f32x16 s0 = {}, s1 = {};
#pragma unroll
    for (int f = 0; f < 4; ++f) s0 = mfma32(ka0[f], qb[f], s0);
#pragma unroll
    for (int f = 0; f < 4; ++f) s1 = mfma32(ka1[f], qb[f], s1);
    // s*[r] = S^T[k = sub*32 + (r&3)+8*(r>>2)+4*hi][q=l31]
    s0 *= SC; s1 *= SC;              // to exp2 domain, in f32

    float mx = fmaxf(vmax16(s0), vmax16(s1));
    mx = fmaxf(mx, __shfl_xor(mx, 32));   // pair (l, l^32) share q = l31

    // exact running max, rescale every tile
    float mn = fmaxf(m_run, mx);
    float al = exp2_fast(m_run - mn);   // first tile: exp2(-huge) = 0
    m_run = mn;
    l_run *= al; o0 *= al; o1 *= al;

#pragma unroll
    for (int i = 0; i < 16; ++i) s0[i] = exp2_fast(s0[i] - m_run);
#pragma unroll
    for (int i = 0; i < 16; ++i) s1[i] = exp2_fast(s1[i] - m_run);

    float sm = vsum16(s0) + vsum16(s1);
    sm += __shfl_xor(sm, 32);
    l_run += sm;

    bf16x8 pb[4];                    // rows 0-15, 16-31 (from s0); 32-47, 48-63 (from s1)
    pack_pb(s0, hi, &pb[0]);
    pack_pb(s1, hi, &pb[2]);

    const u16* vptr = vb_base + kb * 64;
#pragma unroll
    for (int fd = 0; fd < 2; ++fd) {
      const u16* vp = vptr + (size_t)fd * 32 * 1024;
      bf16x8 va00 = *(const bf16x8*)(vp);
      bf16x8 va01 = *(const bf16x8*)(vp + 16);
      bf16x8 va10 = *(const bf16x8*)(vp + 32);
      bf16x8 va11 = *(const bf16x8*)(vp + 48);
      f32x16 oo = fd ? o1 : o0;
      oo = mfma32(va00, pb[0], oo);
      oo = mfma32(va01, pb[1], oo);
      oo = mfma32(va10, pb[2], oo);
      oo = mfma32(va11, pb[3], oo);
      if (fd) o1 = oo; else o0 = oo;
    }
  }

  float inv = 1.0f / l_run;
  o0 *= inv; o1 *= inv;
  // O^T reg r at (fd): d = fd*32 + (r&3) + 8*(r>>2) + 4*hi, q = l31
  u16* crow = ctx + (size_t)(b * 1024 + qg + l31) * 1024 + h * 64 + 4 * hi;
#pragma unroll
  for (int g = 0; g < 4; ++g) {
    u16x4 p0, p1;
#pragma unroll
    for (int j = 0; j < 4; ++j) { p0[j] = f2bf(o0[g * 4 + j]); p1[j] = f2bf(o1[g * 4 + j]); }
    *(u16x4*)(crow + g * 8) = p0;
    *(u16x4*)(crow + 32 + g * 8) = p1;
  }
}

// ------------------------------------------------ LayerNorm (residual fused)
// MODE 0: in1 f32, in2 f32 -> out bf16     (h = LN(x+attn))
// MODE 1: in1 bf16, in2 f32 -> out f32     (out = LN(h+ff2))
template <int MODE>
__global__ __launch_bounds__(256)
void ln_kernel(const void* __restrict__ in1v, const float* __restrict__ in2,
               const float* __restrict__ g, const float* __restrict__ bt,
               void* __restrict__ outv) {
  __shared__ float red[4];
  const int row = blockIdx.x;
  const int t = threadIdx.x;
  const int c = t * 4;
  const size_t base = (size_t)row * 1024 + c;

  float a0, a1, a2, a3;
  {
    const float4 y = *(const float4*)(in2 + base);
    if (MODE == 0) {
      const float4 x = *(const float4*)((const float*)in1v + base);
      a0 = x.x + y.x; a1 = x.y + y.y; a2 = x.z + y.z; a3 = x.w + y.w;
    } else {
      u16x4 xb = *(const u16x4*)((const u16*)in1v + base);
      a0 = bf2f(xb[0]) + y.x; a1 = bf2f(xb[1]) + y.y;
      a2 = bf2f(xb[2]) + y.z; a3 = bf2f(xb[3]) + y.w;
    }
  }
  float sum = waveRedSum(a0 + a1 + a2 + a3);
  if ((t & 63) == 0) red[t >> 6] = sum;
  __syncthreads();
  float mean = (red[0] + red[1] + red[2] + red[3]) * (1.0f / 1024.0f);
  __syncthreads();
  float d0 = a0 - mean, d1 = a1 - mean, d2 = a2 - mean, d3 = a3 - mean;
  float sq = waveRedSum(d0 * d0 + d1 * d1 + d2 * d2 + d3 * d3);
  if ((t & 63) == 0) red[t >> 6] = sq;
  __syncthreads();
  float var = (red[0] + red[1] + red[2] + red[3]) * (1.0f / 1023.0f);
  float inv = rsqrtf(var + 1e-5f);
  const float4 gv = *(const float4*)(g + c);
  const float4 bv = *(const float4*)(bt + c);
  float o0 = d0 * inv * gv.x + bv.x;
  float o1 = d1 * inv * gv.y + bv.y;
  float o2 = d2 * inv * gv.z + bv.z;
  float o3 = d3 * inv * gv.w + bv.w;
  if (MODE == 0) {
    u16x4 ob; ob[0] = f2bf(o0); ob[1] = f2bf(o1); ob[2] = f2bf(o2); ob[3] = f2bf(o3);
    *(u16x4*)((u16*)outv + base) = ob;
  } else {
    float4 of; of.x = o0; of.y = o1; of.z = o2; of.w = o3;
    *(float4*)((float*)outv + base) = of;
  }
}

// ================================================================ launcher
extern "C" void kernel_launch(void* const* d_in, const int* in_sizes, int n_in,
                              void* d_out, int out_size, void* d_ws, size_t ws_size,
                              hipStream_t stream) {
  const float* x  = (const float*)d_in[0];
  const float* Wq = (const float*)d_in[1];
  const float* Wk = (const float*)d_in[2];
  const float* Wv = (const float*)d_in[3];
  const float* Wo = (const float*)d_in[4];
  const float* bo = (const float*)d_in[5];
  const float* g1 = (const float*)d_in[6];
  const float* b1 = (const float*)d_in[7];
  const float* W1 = (const float*)d_in[8];
  const float* c1 = (const float*)d_in[9];
  const float* W2 = (const float*)d_in[10];
  const float* c2 = (const float*)d_in[11];
  const float* g2 = (const float*)d_in[12];
  const float* b2 = (const float*)d_in[13];
  float* out = (float*)d_out;

  // workspace layout (bytes); total use = 142,606,336
  char* ws = (char*)d_ws;
  u16* xb     = (u16*)(ws + 0);           // 16,777,216  (reused as h_b later)
  u16* wqkv_b = (u16*)(ws + 16777216);    //  6,291,456
  u16* wo_b   = (u16*)(ws + 23068672);    //  2,097,152
  u16* w1_b   = (u16*)(ws + 25165824);    //  8,388,608
  u16* w2_b   = (u16*)(ws + 33554432);    //  8,388,608
  char* R1 = ws + 41943040;               // 100,663,296 region, aliased over time
  u16*  qpb  = (u16*)(R1);                 // 16,777,216  live: qkv->attn
  u16*  kpb  = (u16*)(R1 + 16777216);      // 16,777,216  live: qkv->attn
  u16*  vtb  = (u16*)(R1 + 33554432);      // 16,777,216  live: qkv->attn
  u16*  ctx  = (u16*)(R1 + 50331648);      // 16,777,216  live: attn->Wo
  float* attn = (float*)(R1 + 67108864);   // 33,554,432  live: Wo->ln1
  u16*  ff1  = (u16*)(R1);                 // 67,108,864  live: FFN1->FFN2 (aliases qp/kp/vt/ctx)
  float* ff2 = (float*)(R1 + 67108864);    // 33,554,432  live: FFN2->ln2 (aliases attn)
  u16*  h_b  = xb;                         // live: ln1->end (aliases xb)

  cvt_f32_bf16<<<4096, 256, 0, stream>>>(x, xb, 1048576);
  pack_wqkv<<<768, 256, 0, stream>>>(Wq, Wk, Wv, wqkv_b);
  pack_wt<<<256, 256, 0, stream>>>(Wo, wo_b, 1024, 1024);
  pack_wt<<<1024, 256, 0, stream>>>(W1, w1_b, 1024, 4096);
  pack_wt<<<1024, 256, 0, stream>>>(W2, w2_b, 4096, 1024);

  gemm_bt<3><<<64 * 24, 256, 0, stream>>>(xb, wqkv_b, nullptr, nullptr,
                                          8192, 3072, 1024, qpb, kpb, vtb);
  attn32<<<1024, 256, 0, stream>>>(qpb, kpb, vtb, ctx);
  gemm_bt<1><<<64 * 8, 256, 0, stream>>>(ctx, wo_b, attn, bo, 8192, 1024, 1024,
                                         nullptr, nullptr, nullptr);
  ln_kernel<0><<<8192, 256, 0, stream>>>(x, attn, g1, b1, h_b);
  gemm_bt<2><<<64 * 32, 256, 0, stream>>>(h_b, w1_b, ff1, c1, 8192, 4096, 1024,
                                          nullptr, nullptr, nullptr);
  gemm_bt<1><<<64 * 8, 256, 0, stream>>>(ff1, w2_b, ff2, c2, 8192, 1024, 4096,
                                         nullptr, nullptr, nullptr);
  ln_kernel<1><<<8192, 256, 0, stream>>>(h_b, ff2, g2, b2, out);
}

// Round 5
// 451.403 us; speedup vs baseline: 1.2801x; 1.0885x over previous
//
#include <hip/hip_runtime.h>
#include <hip/hip_bf16.h>
#include <math.h>

typedef unsigned short u16;
typedef unsigned int u32;
typedef __attribute__((ext_vector_type(8))) __bf16 bf16x8;
typedef __attribute__((ext_vector_type(4))) float f32x4;
typedef __attribute__((ext_vector_type(16))) float f32x16;
typedef __attribute__((ext_vector_type(8))) u16 u16x8;
typedef __attribute__((ext_vector_type(4))) u16 u16x4;
typedef __attribute__((ext_vector_type(4))) u32 u32x4;

#define DEV static __device__ __forceinline__

DEV u16 f2bf(float x) {
  __bf16 b = (__bf16)x;
  return __builtin_bit_cast(u16, b);
}
DEV float bf2f(u16 u) {
  unsigned v = ((unsigned)u) << 16;
  return __builtin_bit_cast(float, v);
}

DEV void gl_lds16(const u16* g, u16* l) {
  __builtin_amdgcn_global_load_lds(
      (const __attribute__((address_space(1))) void*)g,
      (__attribute__((address_space(3))) void*)l, 16, 0, 0);
}

DEV float waveRedSum(float v) {
  v += __shfl_xor(v, 1);  v += __shfl_xor(v, 2);  v += __shfl_xor(v, 4);
  v += __shfl_xor(v, 8);  v += __shfl_xor(v, 16); v += __shfl_xor(v, 32);
  return v;
}

// --- attention helpers -------------------------------------------------------
DEV float exp2_fast(float x) {
  float r;
  asm("v_exp_f32 %0, %1" : "=v"(r) : "v"(x));
  return r;
}
DEV float vmax16(f32x16 v) {
  float a = fmaxf(v[0], v[1]), b = fmaxf(v[2], v[3]);
  float c = fmaxf(v[4], v[5]), d = fmaxf(v[6], v[7]);
  float e = fmaxf(v[8], v[9]), f = fmaxf(v[10], v[11]);
  float g = fmaxf(v[12], v[13]), h = fmaxf(v[14], v[15]);
  a = fmaxf(a, b); c = fmaxf(c, d); e = fmaxf(e, f); g = fmaxf(g, h);
  return fmaxf(fmaxf(a, c), fmaxf(e, g));
}
DEV float vsum16(f32x16 v) {
  float a = v[0] + v[1], b = v[2] + v[3], c = v[4] + v[5], d = v[6] + v[7];
  float e = v[8] + v[9], f = v[10] + v[11], g = v[12] + v[13], h = v[14] + v[15];
  a += b; c += d; e += f; g += h;
  return (a + c) + (e + g);
}
DEV f32x16 mfma32(bf16x8 a, bf16x8 b, f32x16 c) {
  return __builtin_amdgcn_mfma_f32_32x32x16_bf16(a, b, c, 0, 0, 0);
}
// pack two f32 -> one u32 of two bf16 (elem0 = lo 16 bits), RNE via (__bf16) cast
DEV u32 pack2(float lo, float hi2) {
  return ((u32)f2bf(hi2) << 16) | (u32)f2bf(lo);
}
// P^T -> PV B-fragment, DIRECT register order (no cross-lane ops).
// Valid because vt's s-columns are stored bit2<->bit3-swizzled within each
// 16-group, so the V A-fragment slot (hi,e) holds the same k-row that P's
// natural register order places at slot (hi,e). (Both-sides-same-permutation.)
DEV void pack_direct(const f32x16& s, bf16x8* out) {
  u32x4 f0 = {pack2(s[0], s[1]),   pack2(s[2], s[3]),
              pack2(s[4], s[5]),   pack2(s[6], s[7])};
  u32x4 f1 = {pack2(s[8], s[9]),   pack2(s[10], s[11]),
              pack2(s[12], s[13]), pack2(s[14], s[15])};
  out[0] = __builtin_bit_cast(bf16x8, f0);
  out[1] = __builtin_bit_cast(bf16x8, f1);
}

// ---------------------------------------------------------------- cvt f32->bf16
__global__ __launch_bounds__(256)
void cvt_f32_bf16(const float* __restrict__ in, u16* __restrict__ out, int n8) {
  int i = blockIdx.x * 256 + threadIdx.x;
  if (i >= n8) return;
  const float4 a = *(const float4*)(in + (size_t)i * 8);
  const float4 b = *(const float4*)(in + (size_t)i * 8 + 4);
  u16x8 o;
  o[0] = f2bf(a.x); o[1] = f2bf(a.y); o[2] = f2bf(a.z); o[3] = f2bf(a.w);
  o[4] = f2bf(b.x); o[5] = f2bf(b.y); o[6] = f2bf(b.z); o[7] = f2bf(b.w);
  *(u16x8*)(out + (size_t)i * 8) = o;
}

// ------------------------------------------------ pack Wq/Wk/Wv [H,D,DH] -> bf16 [3072][1024] (N,K)
__global__ __launch_bounds__(256)
void pack_wqkv(const float* __restrict__ Wq, const float* __restrict__ Wk,
               const float* __restrict__ Wv, u16* __restrict__ out) {
  __shared__ float tl[64][65];
  int bid = blockIdx.x;              // 3 * 16 * 16 = 768
  int which = bid / 256;
  int rem = bid % 256;
  int h = rem / 16, dt = rem % 16;
  const float* W = (which == 0) ? Wq : (which == 1) ? Wk : Wv;
  int t = threadIdx.x, tx = t & 63, ty = t >> 6;
  const float* src = W + (size_t)h * 65536 + (size_t)dt * 64 * 64;  // [d][e]
#pragma unroll
  for (int i = 0; i < 16; ++i) {
    int dr = ty * 16 + i;
    tl[dr][tx] = src[(size_t)dr * 64 + tx];
  }
  __syncthreads();
#pragma unroll
  for (int i = 0; i < 16; ++i) {
    int e = ty * 16 + i;
    out[(size_t)(which * 1024 + h * 64 + e) * 1024 + dt * 64 + tx] = f2bf(tl[tx][e]);
  }
}

// ------------------------------------------------ pack W [K][N] -> Wt bf16 [N][K]
__global__ __launch_bounds__(256)
void pack_wt(const float* __restrict__ W, u16* __restrict__ out, int K, int N) {
  __shared__ float tl[64][65];
  int ntiles = N >> 6;
  int kt = blockIdx.x / ntiles, nt = blockIdx.x % ntiles;
  int t = threadIdx.x, tx = t & 63, ty = t >> 6;
#pragma unroll
  for (int i = 0; i < 16; ++i) {
    int kr = ty * 16 + i;
    tl[kr][tx] = W[(size_t)(kt * 64 + kr) * N + nt * 64 + tx];
  }
  __syncthreads();
#pragma unroll
  for (int i = 0; i < 16; ++i) {
    int nr = ty * 16 + i;
    out[(size_t)(nt * 64 + nr) * K + kt * 64 + tx] = f2bf(tl[tx][nr]);
  }
}

// ------------------------------------------------ GEMM: C[M,N] = A[M,K] * Bt[N,K]^T
// EPI: 0 = bf16 out; 1 = f32 out + bias; 2 = bf16 out + bias + exact GELU
// EPI: 3 = QKV pack: q->qp, k->kp, v->vt (transposed, s-cols bit2<->3 swizzled)
template <int EPI>
__global__ __launch_bounds__(256, 2)
void gemm_bt(const u16* __restrict__ A, const u16* __restrict__ Bt,
             void* __restrict__ Cout, const float* __restrict__ bias,
             int M, int N, int K,
             u16* __restrict__ qp_out, u16* __restrict__ kp_out,
             u16* __restrict__ vt_out) {
  __shared__ __align__(16) u16 As[128 * 32];
  __shared__ __align__(16) u16 Bs[128 * 32];
  const int t = threadIdx.x;
  const int lane = t & 63, w = t >> 6;
  const int li = lane & 15, lg = lane >> 4;
  const int tiles_n = N >> 7;
  // T1: bijective XCD-aware swizzle (all grids are multiples of 8)
  const int nwg = gridDim.x;
  const int wgid = (blockIdx.x & 7) * (nwg >> 3) + (blockIdx.x >> 3);
  const int m0 = (wgid / tiles_n) << 7;
  const int n0 = (wgid % tiles_n) << 7;
  const int wm = (w >> 1) << 6, wn = (w & 1) << 6;

  f32x4 acc[4][4] = {};

  const int rowA = t >> 2, kcA = (t & 3) * 8;
  u16* aBase0 = &As[(size_t)(w * 64) * 8];
  u16* aBase1 = &As[(size_t)(256 + w * 64) * 8];
  u16* bBase0 = &Bs[(size_t)(w * 64) * 8];
  u16* bBase1 = &Bs[(size_t)(256 + w * 64) * 8];

  for (int k0 = 0; k0 < K; k0 += 32) {
    gl_lds16(A  + (size_t)(m0 + rowA) * K      + k0 + kcA, aBase0);
    gl_lds16(A  + (size_t)(m0 + 64 + rowA) * K + k0 + kcA, aBase1);
    gl_lds16(Bt + (size_t)(n0 + rowA) * K      + k0 + kcA, bBase0);
    gl_lds16(Bt + (size_t)(n0 + 64 + rowA) * K + k0 + kcA, bBase1);
    __syncthreads();
    bf16x8 af[4], bfr[4];
#pragma unroll
    for (int i = 0; i < 4; ++i)
      af[i] = *(const bf16x8*)&As[(wm + i * 16 + li) * 32 + lg * 8];
#pragma unroll
    for (int i = 0; i < 4; ++i)
      bfr[i] = *(const bf16x8*)&Bs[(wn + i * 16 + li) * 32 + lg * 8];
#pragma unroll
    for (int i = 0; i < 4; ++i)
#pragma unroll
      for (int j = 0; j < 4; ++j)
        acc[i][j] = __builtin_amdgcn_mfma_f32_16x16x32_bf16(af[i], bfr[j], acc[i][j], 0, 0, 0);
    __syncthreads();
  }

  if constexpr (EPI == 3) {
    const int which = n0 >> 10;                 // block-uniform: 0=q 1=k 2=v
    const int colb = (n0 & 1023) + wn + li;     // col within the 1024 group
#pragma unroll
    for (int i = 0; i < 4; ++i) {
      const int row0 = m0 + wm + i * 16 + lg * 4;
      const int bb = row0 >> 10;
      const int s0r = row0 & 1023;
#pragma unroll
      for (int j = 0; j < 4; ++j) {
        const int c = colb + j * 16;
        const int hh = c >> 6, e = c & 63;
        const size_t hb = ((size_t)(bb * 16 + hh)) << 16;   // bh * 1024*64
        if (which == 2) {
          u16x4 pk;
#pragma unroll
          for (int r = 0; r < 4; ++r) pk[r] = f2bf(acc[i][j][r]);
          // swizzle s-position: swap bits 2<->3 within each 16-group
          const int s_sw = (s0r & ~12) | ((s0r & 4) << 1) | ((s0r & 8) >> 1);
          *(u16x4*)(vt_out + hb + ((size_t)e << 10) + s_sw) = pk;
        } else {
          u16* dst = (which == 0) ? qp_out : kp_out;
#pragma unroll
          for (int r = 0; r < 4; ++r)
            dst[hb + (size_t)(s0r + r) * 64 + e] = f2bf(acc[i][j][r]);
        }
      }
    }
    return;
  }

  const int colBase = n0 + wn + li;
#pragma unroll
  for (int i = 0; i < 4; ++i) {
#pragma unroll
    for (int j = 0; j < 4; ++j) {
      int col = colBase + j * 16;
      float bv = (EPI >= 1) ? bias[col] : 0.0f;
#pragma unroll
      for (int r = 0; r < 4; ++r) {
        int row = m0 + wm + i * 16 + lg * 4 + r;
        float v = acc[i][j][r];
        if (EPI >= 1) v += bv;
        if (EPI == 2) v = 0.5f * v * (1.0f + erff(v * 0.70710678118654752f));
        if (EPI == 1) ((float*)Cout)[(size_t)row * N + col] = v;
        else          ((u16*)Cout)[(size_t)row * N + col] = f2bf(v);
      }
    }
  }
}

// ------------------------------------------------ flash attention, 32x32 swapped-QK^T
// qp/kp: [BH][S][64] bf16 (unscaled); vt: [BH][64][S] bf16 (s-cols swizzled)
// ctx: [B*S][1024] bf16.  No LDS, no barriers, no cross-lane P repack.
// Pipelined: V issued at iteration top; K prefetched one tile ahead.
__global__ __launch_bounds__(256, 2)
void attn32(const u16* __restrict__ qp, const u16* __restrict__ kp,
            const u16* __restrict__ vt, u16* __restrict__ ctx) {
  const int t = threadIdx.x, l = t & 63, w = t >> 6;
  const int l31 = l & 31, hi = l >> 5;
  const int bid = blockIdx.x;        // bh*8 + qt
  const int bh = bid >> 3, qt = bid & 7;
  const int b = bh >> 4, h = bh & 15;
  const int qg = qt * 128 + w * 32;  // this wave's q-tile start
  const size_t base = (size_t)bh << 16;
  const float SC = 0.18033688011112042f;  // 0.125 * log2(e)

  // Q as B-fragments: n = q = l31, slot (hi,e) -> k-dim d (consistent with K)
  const u16* qrow = qp + base + (size_t)(qg + l31) * 64 + 8 * hi;
  bf16x8 qb[4];
#pragma unroll
  for (int f = 0; f < 4; ++f) qb[f] = *(const bf16x8*)(qrow + f * 16);

  const u16* kb_base = kp + base + (size_t)l31 * 64 + 8 * hi;
  const u16* vb_base = vt + base + (size_t)l31 * 1024 + 8 * hi;

  f32x16 o0 = {}, o1 = {};           // O^T tiles: d 0-31, 32-63 for q = l31
  float m_run = -1e30f, l_run = 0.0f;

  bf16x8 ka[8];                      // current K tile (prefetched)
#pragma unroll
  for (int f = 0; f < 4; ++f) {
    ka[f]     = *(const bf16x8*)(kb_base + f * 16);
    ka[4 + f] = *(const bf16x8*)(kb_base + 2048 + f * 16);
  }

  for (int kb = 0; kb < 16; ++kb) {
    // issue V loads early — consumed ~400 cycles later in PV
    const u16* vp = vb_base + kb * 64;
    bf16x8 va[8];
#pragma unroll
    for (int c = 0; c < 4; ++c) {
      va[c]     = *(const bf16x8*)(vp + c * 16);
      va[4 + c] = *(const bf16x8*)(vp + 32 * 1024 + c * 16);
    }

    __builtin_amdgcn_s_setprio(1);
    f32x16 s0 = {}, s1 = {};
#pragma unroll
    for (int f = 0; f < 4; ++f) s0 = mfma32(ka[f], qb[f], s0);
#pragma unroll
    for (int f = 0; f < 4; ++f) s1 = mfma32(ka[4 + f], qb[f], s1);
    __builtin_amdgcn_s_setprio(0);
    // s*[r] = S^T[k = sub*32 + (r&3)+8*(r>>2)+4*hi][q=l31]

    // prefetch next K tile; latency hides under softmax + PV
    bf16x8 kn[8];
    if (kb < 15) {
      const u16* kptr = kb_base + (size_t)(kb + 1) * 4096;
#pragma unroll
      for (int f = 0; f < 4; ++f) {
        kn[f]     = *(const bf16x8*)(kptr + f * 16);
        kn[4 + f] = *(const bf16x8*)(kptr + 2048 + f * 16);
      }
    }

    s0 *= SC; s1 *= SC;              // to exp2 domain, in f32

    float mx = fmaxf(vmax16(s0), vmax16(s1));
    mx = fmaxf(mx, __shfl_xor(mx, 32));   // pair (l, l^32) share q = l31

    float mn = fmaxf(m_run, mx);
    float al = exp2_fast(m_run - mn);     // first tile: exp2(-huge) = 0
    m_run = mn;
    l_run *= al; o0 *= al; o1 *= al;

#pragma unroll
    for (int i = 0; i < 16; ++i) s0[i] = exp2_fast(s0[i] - m_run);
#pragma unroll
    for (int i = 0; i < 16; ++i) s1[i] = exp2_fast(s1[i] - m_run);

    float sm = vsum16(s0) + vsum16(s1);
    sm += __shfl_xor(sm, 32);
    l_run += sm;

    bf16x8 pb[4];                    // k rows 0-15,16-31 (s0); 32-47,48-63 (s1)
    pack_direct(s0, &pb[0]);
    pack_direct(s1, &pb[2]);

    __builtin_amdgcn_s_setprio(1);
    o0 = mfma32(va[0], pb[0], o0);
    o0 = mfma32(va[1], pb[1], o0);
    o0 = mfma32(va[2], pb[2], o0);
    o0 = mfma32(va[3], pb[3], o0);
    o1 = mfma32(va[4], pb[0], o1);
    o1 = mfma32(va[5], pb[1], o1);
    o1 = mfma32(va[6], pb[2], o1);
    o1 = mfma32(va[7], pb[3], o1);
    __builtin_amdgcn_s_setprio(0);

    if (kb < 15) {
#pragma unroll
      for (int f = 0; f < 8; ++f) ka[f] = kn[f];
    }
  }

  float inv = 1.0f / l_run;
  o0 *= inv; o1 *= inv;
  // O^T reg r at (fd): d = fd*32 + (r&3) + 8*(r>>2) + 4*hi, q = l31
  u16* crow = ctx + (size_t)(b * 1024 + qg + l31) * 1024 + h * 64 + 4 * hi;
#pragma unroll
  for (int g = 0; g < 4; ++g) {
    u16x4 p0, p1;
#pragma unroll
    for (int j = 0; j < 4; ++j) { p0[j] = f2bf(o0[g * 4 + j]); p1[j] = f2bf(o1[g * 4 + j]); }
    *(u16x4*)(crow + g * 8) = p0;
    *(u16x4*)(crow + 32 + g * 8) = p1;
  }
}

// ------------------------------------------------ LayerNorm (residual fused)
// MODE 0: in1 f32, in2 f32 -> out bf16     (h = LN(x+attn))
// MODE 1: in1 bf16, in2 f32 -> out f32     (out = LN(h+ff2))
template <int MODE>
__global__ __launch_bounds__(256)
void ln_kernel(const void* __restrict__ in1v, const float* __restrict__ in2,
               const float* __restrict__ g, const float* __restrict__ bt,
               void* __restrict__ outv) {
  __shared__ float red[4];
  const int row = blockIdx.x;
  const int t = threadIdx.x;
  const int c = t * 4;
  const size_t base = (size_t)row * 1024 + c;

  float a0, a1, a2, a3;
  {
    const float4 y = *(const float4*)(in2 + base);
    if (MODE == 0) {
      const float4 x = *(const float4*)((const float*)in1v + base);
      a0 = x.x + y.x; a1 = x.y + y.y; a2 = x.z + y.z; a3 = x.w + y.w;
    } else {
      u16x4 xb = *(const u16x4*)((const u16*)in1v + base);
      a0 = bf2f(xb[0]) + y.x; a1 = bf2f(xb[1]) + y.y;
      a2 = bf2f(xb[2]) + y.z; a3 = bf2f(xb[3]) + y.w;
    }
  }
  float sum = waveRedSum(a0 + a1 + a2 + a3);
  if ((t & 63) == 0) red[t >> 6] = sum;
  __syncthreads();
  float mean = (red[0] + red[1] + red[2] + red[3]) * (1.0f / 1024.0f);
  __syncthreads();
  float d0 = a0 - mean, d1 = a1 - mean, d2 = a2 - mean, d3 = a3 - mean;
  float sq = waveRedSum(d0 * d0 + d1 * d1 + d2 * d2 + d3 * d3);
  if ((t & 63) == 0) red[t >> 6] = sq;
  __syncthreads();
  float var = (red[0] + red[1] + red[2] + red[3]) * (1.0f / 1023.0f);
  float inv = rsqrtf(var + 1e-5f);
  const float4 gv = *(const float4*)(g + c);
  const float4 bv = *(const float4*)(bt + c);
  float o0 = d0 * inv * gv.x + bv.x;
  float o1 = d1 * inv * gv.y + bv.y;
  float o2 = d2 * inv * gv.z + bv.z;
  float o3 = d3 * inv * gv.w + bv.w;
  if (MODE == 0) {
    u16x4 ob; ob[0] = f2bf(o0); ob[1] = f2bf(o1); ob[2] = f2bf(o2); ob[3] = f2bf(o3);
    *(u16x4*)((u16*)outv + base) = ob;
  } else {
    float4 of; of.x = o0; of.y = o1; of.z = o2; of.w = o3;
    *(float4*)((float*)outv + base) = of;
  }
}

// ================================================================ launcher
extern "C" void kernel_launch(void* const* d_in, const int* in_sizes, int n_in,
                              void* d_out, int out_size, void* d_ws, size_t ws_size,
                              hipStream_t stream) {
  const float* x  = (const float*)d_in[0];
  const float* Wq = (const float*)d_in[1];
  const float* Wk = (const float*)d_in[2];
  const float* Wv = (const float*)d_in[3];
  const float* Wo = (const float*)d_in[4];
  const float* bo = (const float*)d_in[5];
  const float* g1 = (const float*)d_in[6];
  const float* b1 = (const float*)d_in[7];
  const float* W1 = (const float*)d_in[8];
  const float* c1 = (const float*)d_in[9];
  const float* W2 = (const float*)d_in[10];
  const float* c2 = (const float*)d_in[11];
  const float* g2 = (const float*)d_in[12];
  const float* b2 = (const float*)d_in[13];
  float* out = (float*)d_out;

  // workspace layout (bytes); total use = 142,606,336
  char* ws = (char*)d_ws;
  u16* xb     = (u16*)(ws + 0);           // 16,777,216  (reused as h_b later)
  u16* wqkv_b = (u16*)(ws + 16777216);    //  6,291,456
  u16* wo_b   = (u16*)(ws + 23068672);    //  2,097,152
  u16* w1_b   = (u16*)(ws + 25165824);    //  8,388,608
  u16* w2_b   = (u16*)(ws + 33554432);    //  8,388,608
  char* R1 = ws + 41943040;               // 100,663,296 region, aliased over time
  u16*  qpb  = (u16*)(R1);                 // 16,777,216  live: qkv->attn
  u16*  kpb  = (u16*)(R1 + 16777216);      // 16,777,216  live: qkv->attn
  u16*  vtb  = (u16*)(R1 + 33554432);      // 16,777,216  live: qkv->attn
  u16*  ctx  = (u16*)(R1 + 50331648);      // 16,777,216  live: attn->Wo
  float* attn = (float*)(R1 + 67108864);   // 33,554,432  live: Wo->ln1
  u16*  ff1  = (u16*)(R1);                 // 67,108,864  live: FFN1->FFN2 (aliases qp/kp/vt/ctx)
  float* ff2 = (float*)(R1 + 67108864);    // 33,554,432  live: FFN2->ln2 (aliases attn)
  u16*  h_b  = xb;                         // live: ln1->end (aliases xb)

  cvt_f32_bf16<<<4096, 256, 0, stream>>>(x, xb, 1048576);
  pack_wqkv<<<768, 256, 0, stream>>>(Wq, Wk, Wv, wqkv_b);
  pack_wt<<<256, 256, 0, stream>>>(Wo, wo_b, 1024, 1024);
  pack_wt<<<1024, 256, 0, stream>>>(W1, w1_b, 1024, 4096);
  pack_wt<<<1024, 256, 0, stream>>>(W2, w2_b, 4096, 1024);

  gemm_bt<3><<<64 * 24, 256, 0, stream>>>(xb, wqkv_b, nullptr, nullptr,
                                          8192, 3072, 1024, qpb, kpb, vtb);
  attn32<<<1024, 256, 0, stream>>>(qpb, kpb, vtb, ctx);
  gemm_bt<1><<<64 * 8, 256, 0, stream>>>(ctx, wo_b, attn, bo, 8192, 1024, 1024,
                                         nullptr, nullptr, nullptr);
  ln_kernel<0><<<8192, 256, 0, stream>>>(x, attn, g1, b1, h_b);
  gemm_bt<2><<<64 * 32, 256, 0, stream>>>(h_b, w1_b, ff1, c1, 8192, 4096, 1024,
                                          nullptr, nullptr, nullptr);
  gemm_bt<1><<<64 * 8, 256, 0, stream>>>(ff1, w2_b, ff2, c2, 8192, 1024, 4096,
                                         nullptr, nullptr, nullptr);
  ln_kernel<1><<<8192, 256, 0, stream>>>(h_b, ff2, g2, b2, out);
}

// Round 6
// 390.770 us; speedup vs baseline: 1.4787x; 1.1552x over previous
//
#include <hip/hip_runtime.h>
#include <hip/hip_bf16.h>
#include <math.h>

typedef unsigned short u16;
typedef unsigned int u32;
typedef __attribute__((ext_vector_type(8))) __bf16 bf16x8;
typedef __attribute__((ext_vector_type(4))) float f32x4;
typedef __attribute__((ext_vector_type(16))) float f32x16;
typedef __attribute__((ext_vector_type(8))) u16 u16x8;
typedef __attribute__((ext_vector_type(4))) u16 u16x4;
typedef __attribute__((ext_vector_type(4))) u32 u32x4;

#define DEV static __device__ __forceinline__

DEV u16 f2bf(float x) {
  __bf16 b = (__bf16)x;
  return __builtin_bit_cast(u16, b);
}
DEV float bf2f(u16 u) {
  unsigned v = ((unsigned)u) << 16;
  return __builtin_bit_cast(float, v);
}

DEV void gl_lds16(const u16* g, u16* l) {
  __builtin_amdgcn_global_load_lds(
      (const __attribute__((address_space(1))) void*)g,
      (__attribute__((address_space(3))) void*)l, 16, 0, 0);
}

DEV float waveRedSum(float v) {
  v += __shfl_xor(v, 1);  v += __shfl_xor(v, 2);  v += __shfl_xor(v, 4);
  v += __shfl_xor(v, 8);  v += __shfl_xor(v, 16); v += __shfl_xor(v, 32);
  return v;
}

// --- attention helpers -------------------------------------------------------
DEV float exp2_fast(float x) {
  float r;
  asm("v_exp_f32 %0, %1" : "=v"(r) : "v"(x));
  return r;
}
DEV float vmax16(f32x16 v) {
  float a = fmaxf(v[0], v[1]), b = fmaxf(v[2], v[3]);
  float c = fmaxf(v[4], v[5]), d = fmaxf(v[6], v[7]);
  float e = fmaxf(v[8], v[9]), f = fmaxf(v[10], v[11]);
  float g = fmaxf(v[12], v[13]), h = fmaxf(v[14], v[15]);
  a = fmaxf(a, b); c = fmaxf(c, d); e = fmaxf(e, f); g = fmaxf(g, h);
  return fmaxf(fmaxf(a, c), fmaxf(e, g));
}
DEV float vsum16(f32x16 v) {
  float a = v[0] + v[1], b = v[2] + v[3], c = v[4] + v[5], d = v[6] + v[7];
  float e = v[8] + v[9], f = v[10] + v[11], g = v[12] + v[13], h = v[14] + v[15];
  a += b; c += d; e += f; g += h;
  return (a + c) + (e + g);
}
DEV f32x16 mfma32(bf16x8 a, bf16x8 b, f32x16 c) {
  return __builtin_amdgcn_mfma_f32_32x32x16_bf16(a, b, c, 0, 0, 0);
}
// pack two f32 -> one u32 of two bf16 (elem0 = lo 16 bits), RNE via (__bf16) cast
DEV u32 pack2(float lo, float hi2) {
  return ((u32)f2bf(hi2) << 16) | (u32)f2bf(lo);
}
// P^T -> PV B-fragment, DIRECT register order (no cross-lane ops).
// Valid because vt's s-columns are stored bit2<->bit3-swizzled within each
// 16-group, so the V A-fragment slot (hi,e) holds the same k-row that P's
// natural register order places at slot (hi,e). (Both-sides-same-permutation.)
DEV void pack_direct(const f32x16& s, bf16x8* out) {
  u32x4 f0 = {pack2(s[0], s[1]),   pack2(s[2], s[3]),
              pack2(s[4], s[5]),   pack2(s[6], s[7])};
  u32x4 f1 = {pack2(s[8], s[9]),   pack2(s[10], s[11]),
              pack2(s[12], s[13]), pack2(s[14], s[15])};
  out[0] = __builtin_bit_cast(bf16x8, f0);
  out[1] = __builtin_bit_cast(bf16x8, f1);
}

// ---------------------------------------------------------------- cvt f32->bf16
__global__ __launch_bounds__(256)
void cvt_f32_bf16(const float* __restrict__ in, u16* __restrict__ out, int n8) {
  int i = blockIdx.x * 256 + threadIdx.x;
  if (i >= n8) return;
  const float4 a = *(const float4*)(in + (size_t)i * 8);
  const float4 b = *(const float4*)(in + (size_t)i * 8 + 4);
  u16x8 o;
  o[0] = f2bf(a.x); o[1] = f2bf(a.y); o[2] = f2bf(a.z); o[3] = f2bf(a.w);
  o[4] = f2bf(b.x); o[5] = f2bf(b.y); o[6] = f2bf(b.z); o[7] = f2bf(b.w);
  *(u16x8*)(out + (size_t)i * 8) = o;
}

// ------------------------------------------------ pack Wq/Wk/Wv [H,D,DH] -> bf16 [3072][1024] (N,K)
__global__ __launch_bounds__(256)
void pack_wqkv(const float* __restrict__ Wq, const float* __restrict__ Wk,
               const float* __restrict__ Wv, u16* __restrict__ out) {
  __shared__ float tl[64][65];
  int bid = blockIdx.x;              // 3 * 16 * 16 = 768
  int which = bid / 256;
  int rem = bid % 256;
  int h = rem / 16, dt = rem % 16;
  const float* W = (which == 0) ? Wq : (which == 1) ? Wk : Wv;
  int t = threadIdx.x, tx = t & 63, ty = t >> 6;
  const float* src = W + (size_t)h * 65536 + (size_t)dt * 64 * 64;  // [d][e]
#pragma unroll
  for (int i = 0; i < 16; ++i) {
    int dr = ty * 16 + i;
    tl[dr][tx] = src[(size_t)dr * 64 + tx];
  }
  __syncthreads();
#pragma unroll
  for (int i = 0; i < 16; ++i) {
    int e = ty * 16 + i;
    out[(size_t)(which * 1024 + h * 64 + e) * 1024 + dt * 64 + tx] = f2bf(tl[tx][e]);
  }
}

// ------------------------------------------------ pack W [K][N] -> Wt bf16 [N][K]
__global__ __launch_bounds__(256)
void pack_wt(const float* __restrict__ W, u16* __restrict__ out, int K, int N) {
  __shared__ float tl[64][65];
  int ntiles = N >> 6;
  int kt = blockIdx.x / ntiles, nt = blockIdx.x % ntiles;
  int t = threadIdx.x, tx = t & 63, ty = t >> 6;
#pragma unroll
  for (int i = 0; i < 16; ++i) {
    int kr = ty * 16 + i;
    tl[kr][tx] = W[(size_t)(kt * 64 + kr) * N + nt * 64 + tx];
  }
  __syncthreads();
#pragma unroll
  for (int i = 0; i < 16; ++i) {
    int nr = ty * 16 + i;
    out[(size_t)(nt * 64 + nr) * K + kt * 64 + tx] = f2bf(tl[tx][nr]);
  }
}

// ------------------------------------------------ GEMM: C[M,N] = A[M,K] * Bt[N,K]^T
// EPI: 0 = bf16 out; 1 = f32 out + bias; 2 = bf16 out + bias + exact GELU
// EPI: 3 = QKV pack: q->qp, k->kp, v->vt (transposed, s-cols bit2<->3 swizzled)
template <int EPI>
__global__ __launch_bounds__(256, 2)
void gemm_bt(const u16* __restrict__ A, const u16* __restrict__ Bt,
             void* __restrict__ Cout, const float* __restrict__ bias,
             int M, int N, int K,
             u16* __restrict__ qp_out, u16* __restrict__ kp_out,
             u16* __restrict__ vt_out) {
  __shared__ __align__(16) u16 As[128 * 32];
  __shared__ __align__(16) u16 Bs[128 * 32];
  const int t = threadIdx.x;
  const int lane = t & 63, w = t >> 6;
  const int li = lane & 15, lg = lane >> 4;
  const int tiles_n = N >> 7;
  // T1: bijective XCD-aware swizzle (all grids are multiples of 8)
  const int nwg = gridDim.x;
  const int wgid = (blockIdx.x & 7) * (nwg >> 3) + (blockIdx.x >> 3);
  const int m0 = (wgid / tiles_n) << 7;
  const int n0 = (wgid % tiles_n) << 7;
  const int wm = (w >> 1) << 6, wn = (w & 1) << 6;

  f32x4 acc[4][4] = {};

  const int rowA = t >> 2, kcA = (t & 3) * 8;
  u16* aBase0 = &As[(size_t)(w * 64) * 8];
  u16* aBase1 = &As[(size_t)(256 + w * 64) * 8];
  u16* bBase0 = &Bs[(size_t)(w * 64) * 8];
  u16* bBase1 = &Bs[(size_t)(256 + w * 64) * 8];

  for (int k0 = 0; k0 < K; k0 += 32) {
    gl_lds16(A  + (size_t)(m0 + rowA) * K      + k0 + kcA, aBase0);
    gl_lds16(A  + (size_t)(m0 + 64 + rowA) * K + k0 + kcA, aBase1);
    gl_lds16(Bt + (size_t)(n0 + rowA) * K      + k0 + kcA, bBase0);
    gl_lds16(Bt + (size_t)(n0 + 64 + rowA) * K + k0 + kcA, bBase1);
    __syncthreads();
    bf16x8 af[4], bfr[4];
#pragma unroll
    for (int i = 0; i < 4; ++i)
      af[i] = *(const bf16x8*)&As[(wm + i * 16 + li) * 32 + lg * 8];
#pragma unroll
    for (int i = 0; i < 4; ++i)
      bfr[i] = *(const bf16x8*)&Bs[(wn + i * 16 + li) * 32 + lg * 8];
#pragma unroll
    for (int i = 0; i < 4; ++i)
#pragma unroll
      for (int j = 0; j < 4; ++j)
        acc[i][j] = __builtin_amdgcn_mfma_f32_16x16x32_bf16(af[i], bfr[j], acc[i][j], 0, 0, 0);
    __syncthreads();
  }

  if constexpr (EPI == 3) {
    const int which = n0 >> 10;                 // block-uniform: 0=q 1=k 2=v
    const int colb = (n0 & 1023) + wn + li;     // col within the 1024 group
#pragma unroll
    for (int i = 0; i < 4; ++i) {
      const int row0 = m0 + wm + i * 16 + lg * 4;
      const int bb = row0 >> 10;
      const int s0r = row0 & 1023;
#pragma unroll
      for (int j = 0; j < 4; ++j) {
        const int c = colb + j * 16;
        const int hh = c >> 6, e = c & 63;
        const size_t hb = ((size_t)(bb * 16 + hh)) << 16;   // bh * 1024*64
        if (which == 2) {
          u16x4 pk;
#pragma unroll
          for (int r = 0; r < 4; ++r) pk[r] = f2bf(acc[i][j][r]);
          // swizzle s-position: swap bits 2<->3 within each 16-group
          const int s_sw = (s0r & ~12) | ((s0r & 4) << 1) | ((s0r & 8) >> 1);
          *(u16x4*)(vt_out + hb + ((size_t)e << 10) + s_sw) = pk;
        } else {
          u16* dst = (which == 0) ? qp_out : kp_out;
#pragma unroll
          for (int r = 0; r < 4; ++r)
            dst[hb + (size_t)(s0r + r) * 64 + e] = f2bf(acc[i][j][r]);
        }
      }
    }
    return;
  }

  const int colBase = n0 + wn + li;
#pragma unroll
  for (int i = 0; i < 4; ++i) {
#pragma unroll
    for (int j = 0; j < 4; ++j) {
      int col = colBase + j * 16;
      float bv = (EPI >= 1) ? bias[col] : 0.0f;
#pragma unroll
      for (int r = 0; r < 4; ++r) {
        int row = m0 + wm + i * 16 + lg * 4 + r;
        float v = acc[i][j][r];
        if (EPI >= 1) v += bv;
        if (EPI == 2) v = 0.5f * v * (1.0f + erff(v * 0.70710678118654752f));
        if (EPI == 1) ((float*)Cout)[(size_t)row * N + col] = v;
        else          ((u16*)Cout)[(size_t)row * N + col] = f2bf(v);
      }
    }
  }
}

// ------------------------------------------------ flash attention, 32x32 swapped-QK^T
// qp/kp: [BH][S][64] bf16 (unscaled); vt: [BH][64][S] bf16 (s-cols swizzled)
// ctx: [B*S][1024] bf16.
// K/V tiles staged in LDS (shared by the block's 4 waves), double-buffered,
// slot-major layout [8 d-slots][64 rows]x16B -> conflict-free ds_read_b128.
// XCD-locality remap: all 8 q-tile blocks of one (b,h) land on one XCD.
__global__ __launch_bounds__(256, 2)
void attn32(const u16* __restrict__ qp, const u16* __restrict__ kp,
            const u16* __restrict__ vt, u16* __restrict__ ctx) {
  __shared__ __align__(16) u16 lds[2][2][4096];   // [buf][K=0/V=1][8KB]
  const int t = threadIdx.x, l = t & 63, w = t >> 6;
  const int l31 = l & 31, hi = l >> 5;
  // remap: xcd = bid&7 -> bh in [xcd*16, xcd*16+16)
  const int bid = blockIdx.x;
  const int idx = bid >> 3;                 // 0..127
  const int bh = (bid & 7) * 16 + (idx >> 3);
  const int qt = idx & 7;
  const int b = bh >> 4, h = bh & 15;
  const int qg = qt * 128 + w * 32;         // this wave's q-tile start
  const size_t base = (size_t)bh << 16;
  const float SC = 0.18033688011112042f;    // 0.125 * log2(e)

  // Q as B-fragments: n = q = l31, slot (hi,e) -> k-dim d (consistent with K)
  const u16* qrow = qp + base + (size_t)(qg + l31) * 64 + 8 * hi;
  bf16x8 qb[4];
#pragma unroll
  for (int f = 0; f < 4; ++f) qb[f] = *(const bf16x8*)(qrow + f * 16);

  const u16* kbh = kp + base;               // [64k rows][64d] per tile, tile kb at +kb*4096
  const u16* vbh = vt + base;               // [64d rows][1024s]

  // staging: chunk c = j*256 + w*64 + lane  ->  slot = j*4+w (uniform), row = lane
  // K: LDS[slot][row] <- K[row][8*slot..+8];  V: LDS[slot][row] <- vt[row][kb*64+8*slot..+8]
  const int sl0 = w, sl1 = 4 + w;           // wave-uniform slots for j=0,1

#define STAGE_KV(KB, BUF)                                                        \
  {                                                                              \
    u16* KT = &lds[BUF][0][0];                                                   \
    u16* VT = &lds[BUF][1][0];                                                   \
    const u16* ks = kbh + (size_t)(KB) * 4096;                                   \
    const u16* vs = vbh + (KB) * 64;                                             \
    gl_lds16(ks + (size_t)l * 64 + sl0 * 8,   KT + sl0 * 512);                   \
    gl_lds16(ks + (size_t)l * 64 + sl1 * 8,   KT + sl1 * 512);                   \
    gl_lds16(vs + (size_t)l * 1024 + sl0 * 8, VT + sl0 * 512);                   \
    gl_lds16(vs + (size_t)l * 1024 + sl1 * 8, VT + sl1 * 512);                   \
  }

  f32x16 o0 = {}, o1 = {};           // O^T tiles: d 0-31, 32-63 for q = l31
  float m_run = -1e30f, l_run = 0.0f;

  STAGE_KV(0, 0);
  __syncthreads();

  int buf = 0;
  for (int kb = 0; kb < 16; ++kb) {
    if (kb < 15) STAGE_KV(kb + 1, buf ^ 1);

    const u16* KT = &lds[buf][0][0];
    const u16* VT = &lds[buf][1][0];

    // K A-fragments: row = l31 (+32), d-slot = 2f+hi -> contiguous 16B reads
    bf16x8 ka[8];
#pragma unroll
    for (int f = 0; f < 4; ++f) {
      const int so = (2 * f + hi) * 512 + l31 * 8;
      ka[f]     = *(const bf16x8*)&KT[so];
      ka[4 + f] = *(const bf16x8*)&KT[so + 256];
    }

    __builtin_amdgcn_s_setprio(1);
    f32x16 s0 = {}, s1 = {};
#pragma unroll
    for (int f = 0; f < 4; ++f) s0 = mfma32(ka[f], qb[f], s0);
#pragma unroll
    for (int f = 0; f < 4; ++f) s1 = mfma32(ka[4 + f], qb[f], s1);
    __builtin_amdgcn_s_setprio(0);
    // s*[r] = S^T[k = sub*32 + (r&3)+8*(r>>2)+4*hi][q=l31]

    // V A-fragments (consumed after softmax; ds latency hides under VALU)
    bf16x8 va[8];
#pragma unroll
    for (int c = 0; c < 4; ++c) {
      const int so = (2 * c + hi) * 512 + l31 * 8;
      va[c]     = *(const bf16x8*)&VT[so];
      va[4 + c] = *(const bf16x8*)&VT[so + 256];
    }

    s0 *= SC; s1 *= SC;              // to exp2 domain, in f32

    float mx = fmaxf(vmax16(s0), vmax16(s1));
    mx = fmaxf(mx, __shfl_xor(mx, 32));   // pair (l, l^32) share q = l31

    float mn = fmaxf(m_run, mx);
    float al = exp2_fast(m_run - mn);     // first tile: exp2(-huge) = 0
    m_run = mn;
    l_run *= al; o0 *= al; o1 *= al;

#pragma unroll
    for (int i = 0; i < 16; ++i) s0[i] = exp2_fast(s0[i] - m_run);
#pragma unroll
    for (int i = 0; i < 16; ++i) s1[i] = exp2_fast(s1[i] - m_run);

    float sm = vsum16(s0) + vsum16(s1);
    sm += __shfl_xor(sm, 32);
    l_run += sm;

    bf16x8 pb[4];                    // k rows 0-15,16-31 (s0); 32-47,48-63 (s1)
    pack_direct(s0, &pb[0]);
    pack_direct(s1, &pb[2]);

    __builtin_amdgcn_s_setprio(1);
    o0 = mfma32(va[0], pb[0], o0);
    o0 = mfma32(va[1], pb[1], o0);
    o0 = mfma32(va[2], pb[2], o0);
    o0 = mfma32(va[3], pb[3], o0);
    o1 = mfma32(va[4], pb[0], o1);
    o1 = mfma32(va[5], pb[1], o1);
    o1 = mfma32(va[6], pb[2], o1);
    o1 = mfma32(va[7], pb[3], o1);
    __builtin_amdgcn_s_setprio(0);

    __syncthreads();                 // next-tile staged + all waves done with buf
    buf ^= 1;
  }
#undef STAGE_KV

  float inv = 1.0f / l_run;
  o0 *= inv; o1 *= inv;
  // O^T reg r at (fd): d = fd*32 + (r&3) + 8*(r>>2) + 4*hi, q = l31
  u16* crow = ctx + (size_t)(b * 1024 + qg + l31) * 1024 + h * 64 + 4 * hi;
#pragma unroll
  for (int g = 0; g < 4; ++g) {
    u16x4 p0, p1;
#pragma unroll
    for (int j = 0; j < 4; ++j) { p0[j] = f2bf(o0[g * 4 + j]); p1[j] = f2bf(o1[g * 4 + j]); }
    *(u16x4*)(crow + g * 8) = p0;
    *(u16x4*)(crow + 32 + g * 8) = p1;
  }
}

// ------------------------------------------------ LayerNorm (residual fused)
// MODE 0: in1 f32, in2 f32 -> out bf16     (h = LN(x+attn))
// MODE 1: in1 bf16, in2 f32 -> out f32     (out = LN(h+ff2))
template <int MODE>
__global__ __launch_bounds__(256)
void ln_kernel(const void* __restrict__ in1v, const float* __restrict__ in2,
               const float* __restrict__ g, const float* __restrict__ bt,
               void* __restrict__ outv) {
  __shared__ float red[4];
  const int row = blockIdx.x;
  const int t = threadIdx.x;
  const int c = t * 4;
  const size_t base = (size_t)row * 1024 + c;

  float a0, a1, a2, a3;
  {
    const float4 y = *(const float4*)(in2 + base);
    if (MODE == 0) {
      const float4 x = *(const float4*)((const float*)in1v + base);
      a0 = x.x + y.x; a1 = x.y + y.y; a2 = x.z + y.z; a3 = x.w + y.w;
    } else {
      u16x4 xb = *(const u16x4*)((const u16*)in1v + base);
      a0 = bf2f(xb[0]) + y.x; a1 = bf2f(xb[1]) + y.y;
      a2 = bf2f(xb[2]) + y.z; a3 = bf2f(xb[3]) + y.w;
    }
  }
  float sum = waveRedSum(a0 + a1 + a2 + a3);
  if ((t & 63) == 0) red[t >> 6] = sum;
  __syncthreads();
  float mean = (red[0] + red[1] + red[2] + red[3]) * (1.0f / 1024.0f);
  __syncthreads();
  float d0 = a0 - mean, d1 = a1 - mean, d2 = a2 - mean, d3 = a3 - mean;
  float sq = waveRedSum(d0 * d0 + d1 * d1 + d2 * d2 + d3 * d3);
  if ((t & 63) == 0) red[t >> 6] = sq;
  __syncthreads();
  float var = (red[0] + red[1] + red[2] + red[3]) * (1.0f / 1023.0f);
  float inv = rsqrtf(var + 1e-5f);
  const float4 gv = *(const float4*)(g + c);
  const float4 bv = *(const float4*)(bt + c);
  float o0 = d0 * inv * gv.x + bv.x;
  float o1 = d1 * inv * gv.y + bv.y;
  float o2 = d2 * inv * gv.z + bv.z;
  float o3 = d3 * inv * gv.w + bv.w;
  if (MODE == 0) {
    u16x4 ob; ob[0] = f2bf(o0); ob[1] = f2bf(o1); ob[2] = f2bf(o2); ob[3] = f2bf(o3);
    *(u16x4*)((u16*)outv + base) = ob;
  } else {
    float4 of; of.x = o0; of.y = o1; of.z = o2; of.w = o3;
    *(float4*)((float*)outv + base) = of;
  }
}

// ================================================================ launcher
extern "C" void kernel_launch(void* const* d_in, const int* in_sizes, int n_in,
                              void* d_out, int out_size, void* d_ws, size_t ws_size,
                              hipStream_t stream) {
  const float* x  = (const float*)d_in[0];
  const float* Wq = (const float*)d_in[1];
  const float* Wk = (const float*)d_in[2];
  const float* Wv = (const float*)d_in[3];
  const float* Wo = (const float*)d_in[4];
  const float* bo = (const float*)d_in[5];
  const float* g1 = (const float*)d_in[6];
  const float* b1 = (const float*)d_in[7];
  const float* W1 = (const float*)d_in[8];
  const float* c1 = (const float*)d_in[9];
  const float* W2 = (const float*)d_in[10];
  const float* c2 = (const float*)d_in[11];
  const float* g2 = (const float*)d_in[12];
  const float* b2 = (const float*)d_in[13];
  float* out = (float*)d_out;

  // workspace layout (bytes); total use = 142,606,336
  char* ws = (char*)d_ws;
  u16* xb     = (u16*)(ws + 0);           // 16,777,216  (reused as h_b later)
  u16* wqkv_b = (u16*)(ws + 16777216);    //  6,291,456
  u16* wo_b   = (u16*)(ws + 23068672);    //  2,097,152
  u16* w1_b   = (u16*)(ws + 25165824);    //  8,388,608
  u16* w2_b   = (u16*)(ws + 33554432);    //  8,388,608
  char* R1 = ws + 41943040;               // 100,663,296 region, aliased over time
  u16*  qpb  = (u16*)(R1);                 // 16,777,216  live: qkv->attn
  u16*  kpb  = (u16*)(R1 + 16777216);      // 16,777,216  live: qkv->attn
  u16*  vtb  = (u16*)(R1 + 33554432);      // 16,777,216  live: qkv->attn
  u16*  ctx  = (u16*)(R1 + 50331648);      // 16,777,216  live: attn->Wo
  float* attn = (float*)(R1 + 67108864);   // 33,554,432  live: Wo->ln1
  u16*  ff1  = (u16*)(R1);                 // 67,108,864  live: FFN1->FFN2 (aliases qp/kp/vt/ctx)
  float* ff2 = (float*)(R1 + 67108864);    // 33,554,432  live: FFN2->ln2 (aliases attn)
  u16*  h_b  = xb;                         // live: ln1->end (aliases xb)

  cvt_f32_bf16<<<4096, 256, 0, stream>>>(x, xb, 1048576);
  pack_wqkv<<<768, 256, 0, stream>>>(Wq, Wk, Wv, wqkv_b);
  pack_wt<<<256, 256, 0, stream>>>(Wo, wo_b, 1024, 1024);
  pack_wt<<<1024, 256, 0, stream>>>(W1, w1_b, 1024, 4096);
  pack_wt<<<1024, 256, 0, stream>>>(W2, w2_b, 4096, 1024);

  gemm_bt<3><<<64 * 24, 256, 0, stream>>>(xb, wqkv_b, nullptr, nullptr,
                                          8192, 3072, 1024, qpb, kpb, vtb);
  attn32<<<1024, 256, 0, stream>>>(qpb, kpb, vtb, ctx);
  gemm_bt<1><<<64 * 8, 256, 0, stream>>>(ctx, wo_b, attn, bo, 8192, 1024, 1024,
                                         nullptr, nullptr, nullptr);
  ln_kernel<0><<<8192, 256, 0, stream>>>(x, attn, g1, b1, h_b);
  gemm_bt<2><<<64 * 32, 256, 0, stream>>>(h_b, w1_b, ff1, c1, 8192, 4096, 1024,
                                          nullptr, nullptr, nullptr);
  gemm_bt<1><<<64 * 8, 256, 0, stream>>>(ff1, w2_b, ff2, c2, 8192, 1024, 4096,
                                         nullptr, nullptr, nullptr);
  ln_kernel<1><<<8192, 256, 0, stream>>>(h_b, ff2, g2, b2, out);
}